// Round 2
// baseline (120.865 us; speedup 1.0000x reference)
//
#include <hip/hip_runtime.h>
#include <hip/hip_bf16.h>

#define NN 512          // nodes
#define IND 512         // in features
#define NH 8            // heads
#define NF 64           // hidden per head
#define NEG_SLOPE 0.2f

// ---------------------------------------------------------------------------
// K1: Gs = X @ Ws^T, Gt = X @ Wt^T   (fp32 in, fp32 out in workspace)
// C[n,o] = sum_k X[n,k] * W[o,k]; 32x32 tile per block, 2x2 per thread.
// ---------------------------------------------------------------------------
__global__ __launch_bounds__(256) void gemm_xwT(
    const float* __restrict__ X,
    const float* __restrict__ Ws,
    const float* __restrict__ Wt,
    float* __restrict__ Gs, float* __restrict__ Gt)
{
    const float* W = (blockIdx.z == 0) ? Ws : Wt;
    float* C = (blockIdx.z == 0) ? Gs : Gt;

    __shared__ float As[32][33];
    __shared__ float Bs[32][33];

    const int tid = threadIdx.x;
    const int n0 = blockIdx.y * 32;
    const int o0 = blockIdx.x * 32;
    const int row = tid >> 3;          // 0..31
    const int kg  = (tid & 7) * 4;     // 0..28 step 4
    const int ty = tid >> 4;           // 0..15
    const int tx = tid & 15;           // 0..15

    float c00 = 0.f, c01 = 0.f, c10 = 0.f, c11 = 0.f;

    for (int kt = 0; kt < IND; kt += 32) {
        float4 pa = *reinterpret_cast<const float4*>(X + (size_t)(n0 + row) * IND + kt + kg);
        As[row][kg + 0] = pa.x;
        As[row][kg + 1] = pa.y;
        As[row][kg + 2] = pa.z;
        As[row][kg + 3] = pa.w;
        float4 pb = *reinterpret_cast<const float4*>(W + (size_t)(o0 + row) * IND + kt + kg);
        Bs[row][kg + 0] = pb.x;
        Bs[row][kg + 1] = pb.y;
        Bs[row][kg + 2] = pb.z;
        Bs[row][kg + 3] = pb.w;
        __syncthreads();
        #pragma unroll
        for (int k = 0; k < 32; ++k) {
            float a0 = As[ty][k], a1 = As[ty + 16][k];
            float b0 = Bs[tx][k], b1 = Bs[tx + 16][k];
            c00 += a0 * b0; c01 += a0 * b1;
            c10 += a1 * b0; c11 += a1 * b1;
        }
        __syncthreads();
    }
    C[(size_t)(n0 + ty) * IND + o0 + tx]            = c00;
    C[(size_t)(n0 + ty) * IND + o0 + tx + 16]       = c01;
    C[(size_t)(n0 + ty + 16) * IND + o0 + tx]       = c10;
    C[(size_t)(n0 + ty + 16) * IND + o0 + tx + 16]  = c11;
}

// ---------------------------------------------------------------------------
// K2: per (i-tile of 4, head h) block:
//   scores[ii][j] = sum_f lrelu(Gs[j,h,f] + Gt[i0+ii,h,f]) * w[f]  (adj mask)
//   softmax over j (one wave per ii row), write attention (fp32),
//   head_output[i,h,f] = sum_j att * Gt[j,h,f], write out (fp32).
// G layout: G[n*512 + h*64 + f] (fp32).
// ---------------------------------------------------------------------------
__global__ __launch_bounds__(256) void gat_attn(
    const float* __restrict__ Gs, const float* __restrict__ Gt,
    const float* __restrict__ attn_w,
    const int* __restrict__ adj,
    float* __restrict__ out_feat,   // [512, 512]
    float* __restrict__ out_att)    // [512, 512, 8]
{
    __shared__ float s_gt[4][64];
    __shared__ float s_w[64];
    __shared__ float s_sc[4][512];
    __shared__ float s_red[4][4][64];

    const int tid = threadIdx.x;
    const int i0 = blockIdx.x * 4;
    const int h  = blockIdx.y;

    {
        int ii = tid >> 6, f = tid & 63;
        s_gt[ii][f] = Gt[(size_t)(i0 + ii) * IND + h * NF + f];
        if (tid < 64) s_w[tid] = attn_w[tid];
    }
    __syncthreads();

    // ---- phase 1: scores ----
    #pragma unroll
    for (int rep = 0; rep < 2; ++rep) {
        int j = tid + rep * 256;
        float a0 = 0.f, a1 = 0.f, a2 = 0.f, a3 = 0.f;
        const float4* gp = reinterpret_cast<const float4*>(Gs + (size_t)j * IND + h * NF);
        #pragma unroll 4
        for (int f4 = 0; f4 < 16; ++f4) {
            float4 g = gp[f4];
            #pragma unroll
            for (int c = 0; c < 4; ++c) {
                float gv = (c == 0) ? g.x : (c == 1) ? g.y : (c == 2) ? g.z : g.w;
                int f = f4 * 4 + c;
                float w = s_w[f];
                float t;
                t = gv + s_gt[0][f]; t = (t >= 0.f) ? t : NEG_SLOPE * t; a0 += t * w;
                t = gv + s_gt[1][f]; t = (t >= 0.f) ? t : NEG_SLOPE * t; a1 += t * w;
                t = gv + s_gt[2][f]; t = (t >= 0.f) ? t : NEG_SLOPE * t; a2 += t * w;
                t = gv + s_gt[3][f]; t = (t >= 0.f) ? t : NEG_SLOPE * t; a3 += t * w;
            }
        }
        s_sc[0][j] = adj[(size_t)(i0 + 0) * NN + j] ? a0 : -INFINITY;
        s_sc[1][j] = adj[(size_t)(i0 + 1) * NN + j] ? a1 : -INFINITY;
        s_sc[2][j] = adj[(size_t)(i0 + 2) * NN + j] ? a2 : -INFINITY;
        s_sc[3][j] = adj[(size_t)(i0 + 3) * NN + j] ? a3 : -INFINITY;
    }
    __syncthreads();

    // ---- phase 2: softmax (wave per row) + attention write ----
    {
        const int wave = tid >> 6, lane = tid & 63;
        const int ii = wave;
        float m = -INFINITY;
        #pragma unroll
        for (int r = 0; r < 8; ++r) m = fmaxf(m, s_sc[ii][lane + r * 64]);
        #pragma unroll
        for (int off = 32; off >= 1; off >>= 1) m = fmaxf(m, __shfl_xor(m, off, 64));
        float e[8];
        float sum = 0.f;
        #pragma unroll
        for (int r = 0; r < 8; ++r) {
            float v = s_sc[ii][lane + r * 64];
            float ev = __expf(v - m);
            e[r] = ev;
            sum += ev;
        }
        #pragma unroll
        for (int off = 32; off >= 1; off >>= 1) sum += __shfl_xor(sum, off, 64);
        float inv = 1.f / sum;
        int i = i0 + ii;
        #pragma unroll
        for (int r = 0; r < 8; ++r) {
            int j = lane + r * 64;
            float a = e[r] * inv;
            s_sc[ii][j] = a;
            out_att[((size_t)i * NN + j) * NH + h] = a;
        }
    }
    __syncthreads();

    // ---- phase 3: head_output = att @ Gt ----
    {
        const int f = tid & 63, q = tid >> 6;
        float a0 = 0.f, a1 = 0.f, a2 = 0.f, a3 = 0.f;
        for (int j = q * 128; j < q * 128 + 128; ++j) {
            float gv = Gt[(size_t)j * IND + h * NF + f];
            a0 += s_sc[0][j] * gv;
            a1 += s_sc[1][j] * gv;
            a2 += s_sc[2][j] * gv;
            a3 += s_sc[3][j] * gv;
        }
        s_red[q][0][f] = a0; s_red[q][1][f] = a1;
        s_red[q][2][f] = a2; s_red[q][3][f] = a3;
    }
    __syncthreads();
    {
        int ii = tid >> 6, f = tid & 63;
        float s = s_red[0][ii][f] + s_red[1][ii][f] + s_red[2][ii][f] + s_red[3][ii][f];
        out_feat[(size_t)(i0 + ii) * (NH * NF) + h * NF + f] = s;
    }
}

extern "C" void kernel_launch(void* const* d_in, const int* in_sizes, int n_in,
                              void* d_out, int out_size, void* d_ws, size_t ws_size,
                              hipStream_t stream) {
    const float* X  = (const float*)d_in[0];   // h [1,512,512] fp32
    const float* Ws = (const float*)d_in[1];   // W_source [512,512] fp32
    const float* Wt = (const float*)d_in[2];   // W_target [512,512] fp32
    const float* aw = (const float*)d_in[3];   // attn_w [64] fp32
    const int* adj  = (const int*)d_in[4];     // adjacency [512,512,1] int32

    float* Gs = (float*)d_ws;            // [512,512] fp32
    float* Gt = Gs + (size_t)NN * IND;   // [512,512] fp32

    float* out_feat = (float*)d_out;                      // [512,512]
    float* out_att  = out_feat + (size_t)NN * NH * NF;    // [512,512,8]

    hipLaunchKernelGGL(gemm_xwT, dim3(16, 16, 2), dim3(256), 0, stream,
                       X, Ws, Wt, Gs, Gt);
    hipLaunchKernelGGL(gat_attn, dim3(NN / 4, NH), dim3(256), 0, stream,
                       Gs, Gt, aw, adj, out_feat, out_att);
}

// Round 3
// 108.631 us; speedup vs baseline: 1.1126x; 1.1126x over previous
//
#include <hip/hip_runtime.h>

#define NN 512          // nodes
#define IND 512         // in features
#define NH 8            // heads
#define NF 64           // hidden per head

// ---------------------------------------------------------------------------
// K0: 512x512 fp32 transpose (z=0: X -> Xt, z=1: W_target -> Wtg_t)
// ---------------------------------------------------------------------------
__global__ __launch_bounds__(256) void transpose512(
    const float* __restrict__ X, float* __restrict__ Xt,
    const float* __restrict__ Wtg, float* __restrict__ Wtg_t)
{
    const float* src = blockIdx.z ? Wtg : X;
    float* dst       = blockIdx.z ? Wtg_t : Xt;
    __shared__ float tile[32][33];
    const int tid = threadIdx.x;
    const int tx = tid & 31, ty4 = (tid >> 5) * 4;
    const int x  = blockIdx.x * 32 + tx;
    const int y0 = blockIdx.y * 32 + ty4;
    #pragma unroll
    for (int r = 0; r < 4; ++r)
        tile[ty4 + r][tx] = src[(size_t)(y0 + r) * NN + x];
    __syncthreads();
    const int xo  = blockIdx.y * 32 + tx;
    const int yo0 = blockIdx.x * 32 + ty4;
    #pragma unroll
    for (int r = 0; r < 4; ++r)
        dst[(size_t)(yo0 + r) * NN + xo] = tile[tx][ty4 + r];
}

// ---------------------------------------------------------------------------
// K1: TN GEMM, no LDS staging: C[r][c] = sum_k S[r][k] * V[k][c]
//   S row-operand: wave-uniform address -> s_load through K$
//   V col-operand: lanes on c -> coalesced global_load_dwordx2
// z=0: Gs_t[o][n] = sum_k Ws[o][k]  * Xt[k][n]     (S=Ws, V=Xt)
// z=1: Gt  [n][o] = sum_k X [n][k]  * Wtg_t[k][o]  (S=X,  V=Wtg_t)
// Block: 128 cols x 8 rows; 4 waves = 2 row-groups x 2 k-halves (split-K,
// LDS-reduced) -> 512 blocks total = 2 blocks/CU, 2 waves/SIMD.
// ---------------------------------------------------------------------------
__global__ __launch_bounds__(256) void gemm_tn(
    const float* __restrict__ Sa, const float* __restrict__ Va, float* __restrict__ Ca,
    const float* __restrict__ Sb, const float* __restrict__ Vb, float* __restrict__ Cb)
{
    const float* S = blockIdx.z ? Sb : Sa;
    const float* V = blockIdx.z ? Vb : Va;
    float*       C = blockIdx.z ? Cb : Ca;

    __shared__ float2 sp[2][4][64];

    const int tid  = threadIdx.x;
    const int wv   = __builtin_amdgcn_readfirstlane(tid >> 6);
    const int lane = tid & 63;
    const int rg = wv & 1, kh = wv >> 1;
    const int r0 = blockIdx.y * 8 + rg * 4;
    const int c0 = blockIdx.x * 128 + lane * 2;

    const float* Sp = S + (size_t)r0 * IND + kh * 256;
    const float* Vp = V + (size_t)kh * 256 * NN + c0;

    float2 a0 = {0.f, 0.f}, a1 = {0.f, 0.f}, a2 = {0.f, 0.f}, a3 = {0.f, 0.f};
    #pragma unroll 8
    for (int k = 0; k < 256; ++k) {
        float2 v = *reinterpret_cast<const float2*>(Vp + (size_t)k * NN);
        float s0 = Sp[k];
        float s1 = Sp[IND + k];
        float s2 = Sp[2 * IND + k];
        float s3 = Sp[3 * IND + k];
        a0.x = fmaf(s0, v.x, a0.x); a0.y = fmaf(s0, v.y, a0.y);
        a1.x = fmaf(s1, v.x, a1.x); a1.y = fmaf(s1, v.y, a1.y);
        a2.x = fmaf(s2, v.x, a2.x); a2.y = fmaf(s2, v.y, a2.y);
        a3.x = fmaf(s3, v.x, a3.x); a3.y = fmaf(s3, v.y, a3.y);
    }
    if (kh) {
        sp[rg][0][lane] = a0; sp[rg][1][lane] = a1;
        sp[rg][2][lane] = a2; sp[rg][3][lane] = a3;
    }
    __syncthreads();
    if (!kh) {
        float2 p;
        p = sp[rg][0][lane]; a0.x += p.x; a0.y += p.y;
        p = sp[rg][1][lane]; a1.x += p.x; a1.y += p.y;
        p = sp[rg][2][lane]; a2.x += p.x; a2.y += p.y;
        p = sp[rg][3][lane]; a3.x += p.x; a3.y += p.y;
        *reinterpret_cast<float2*>(C + (size_t)(r0 + 0) * NN + c0) = a0;
        *reinterpret_cast<float2*>(C + (size_t)(r0 + 1) * NN + c0) = a1;
        *reinterpret_cast<float2*>(C + (size_t)(r0 + 2) * NN + c0) = a2;
        *reinterpret_cast<float2*>(C + (size_t)(r0 + 3) * NN + c0) = a3;
    }
}

// ---------------------------------------------------------------------------
// K2: per (i-tile of 4, head h) block.
//   phase 1: scores from Gs_t (coalesced over j) + uniform s_loads of Gt/w.
//            w*lrelu(t) = 0.6w*t + 0.4w*|t|  (3 VALU/elem, |t| is free mod)
//   phase 2: softmax over j, one wave per row; write attention.
//   phase 3: head_output = att @ Gt; att via uniform-address ds_read_b128.
// ---------------------------------------------------------------------------
__global__ __launch_bounds__(256) void gat_attn(
    const float* __restrict__ Gs_t,      // [512 (h*64+f)][512 j]
    const float* __restrict__ Gt,        // [512 n][512 (h*64+f)]
    const float* __restrict__ attn_w,    // [64]
    const int*   __restrict__ adj,       // [512][512]
    float* __restrict__ out_feat,        // [512][512]
    float* __restrict__ out_att)         // [512][512][8]
{
    __shared__ float s_sc[4][512];
    __shared__ float s_red[4][4][64];

    const int tid = threadIdx.x;
    const int i0  = blockIdx.x * 4;
    const int h   = blockIdx.y;

    // ---- phase 1: scores (2 j's per thread via float2) ----
    {
        const int jj = tid * 2;
        float2 acc0 = {0.f,0.f}, acc1 = {0.f,0.f}, acc2 = {0.f,0.f}, acc3 = {0.f,0.f};
        const float* gsp = Gs_t + (size_t)h * NF * NN + jj;
        const float* gtp = Gt + (size_t)i0 * IND + h * NF;
        #pragma unroll 4
        for (int f = 0; f < NF; ++f) {
            float w  = attn_w[f];            // uniform -> s_load
            float w6 = 0.6f * w, w4 = 0.4f * w;
            float2 g = *reinterpret_cast<const float2*>(gsp + (size_t)f * NN);
            float gt0 = gtp[f];              // uniform -> s_load
            float gt1 = gtp[IND + f];
            float gt2 = gtp[2 * IND + f];
            float gt3 = gtp[3 * IND + f];
            float tx, ty;
            tx = g.x + gt0; ty = g.y + gt0;
            acc0.x = fmaf(w4, fabsf(tx), fmaf(w6, tx, acc0.x));
            acc0.y = fmaf(w4, fabsf(ty), fmaf(w6, ty, acc0.y));
            tx = g.x + gt1; ty = g.y + gt1;
            acc1.x = fmaf(w4, fabsf(tx), fmaf(w6, tx, acc1.x));
            acc1.y = fmaf(w4, fabsf(ty), fmaf(w6, ty, acc1.y));
            tx = g.x + gt2; ty = g.y + gt2;
            acc2.x = fmaf(w4, fabsf(tx), fmaf(w6, tx, acc2.x));
            acc2.y = fmaf(w4, fabsf(ty), fmaf(w6, ty, acc2.y));
            tx = g.x + gt3; ty = g.y + gt3;
            acc3.x = fmaf(w4, fabsf(tx), fmaf(w6, tx, acc3.x));
            acc3.y = fmaf(w4, fabsf(ty), fmaf(w6, ty, acc3.y));
        }
        int2 ad;
        ad = *reinterpret_cast<const int2*>(adj + (size_t)(i0 + 0) * NN + jj);
        s_sc[0][jj]     = ad.x ? acc0.x : -INFINITY;
        s_sc[0][jj + 1] = ad.y ? acc0.y : -INFINITY;
        ad = *reinterpret_cast<const int2*>(adj + (size_t)(i0 + 1) * NN + jj);
        s_sc[1][jj]     = ad.x ? acc1.x : -INFINITY;
        s_sc[1][jj + 1] = ad.y ? acc1.y : -INFINITY;
        ad = *reinterpret_cast<const int2*>(adj + (size_t)(i0 + 2) * NN + jj);
        s_sc[2][jj]     = ad.x ? acc2.x : -INFINITY;
        s_sc[2][jj + 1] = ad.y ? acc2.y : -INFINITY;
        ad = *reinterpret_cast<const int2*>(adj + (size_t)(i0 + 3) * NN + jj);
        s_sc[3][jj]     = ad.x ? acc3.x : -INFINITY;
        s_sc[3][jj + 1] = ad.y ? acc3.y : -INFINITY;
    }
    __syncthreads();

    // ---- phase 2: softmax (one wave per row) + attention write ----
    {
        const int ii = tid >> 6, lane = tid & 63;
        float m = -INFINITY;
        #pragma unroll
        for (int r = 0; r < 8; ++r) m = fmaxf(m, s_sc[ii][lane + r * 64]);
        #pragma unroll
        for (int off = 32; off >= 1; off >>= 1) m = fmaxf(m, __shfl_xor(m, off, 64));
        float e[8];
        float sum = 0.f;
        #pragma unroll
        for (int r = 0; r < 8; ++r) {
            float ev = __expf(s_sc[ii][lane + r * 64] - m);
            e[r] = ev;
            sum += ev;
        }
        #pragma unroll
        for (int off = 32; off >= 1; off >>= 1) sum += __shfl_xor(sum, off, 64);
        float inv = 1.f / sum;
        const int i = i0 + ii;
        #pragma unroll
        for (int r = 0; r < 8; ++r) {
            int j = lane + r * 64;
            float a = e[r] * inv;
            s_sc[ii][j] = a;
            out_att[((size_t)i * NN + j) * NH + h] = a;
        }
    }
    __syncthreads();

    // ---- phase 3: head_output = att @ Gt (waves split j; b128 att broadcast) ----
    {
        const int w = tid >> 6, lane = tid & 63;
        const int jb = w * 128;
        float o0 = 0.f, o1 = 0.f, o2 = 0.f, o3 = 0.f;
        const float* gtc = Gt + h * NF + lane;
        #pragma unroll 4
        for (int s = 0; s < 32; ++s) {
            const int j = jb + 4 * s;
            float4 b0 = *reinterpret_cast<const float4*>(&s_sc[0][j]);
            float4 b1 = *reinterpret_cast<const float4*>(&s_sc[1][j]);
            float4 b2 = *reinterpret_cast<const float4*>(&s_sc[2][j]);
            float4 b3 = *reinterpret_cast<const float4*>(&s_sc[3][j]);
            float gv;
            gv = gtc[(size_t)(j + 0) * IND];
            o0 = fmaf(b0.x, gv, o0); o1 = fmaf(b1.x, gv, o1);
            o2 = fmaf(b2.x, gv, o2); o3 = fmaf(b3.x, gv, o3);
            gv = gtc[(size_t)(j + 1) * IND];
            o0 = fmaf(b0.y, gv, o0); o1 = fmaf(b1.y, gv, o1);
            o2 = fmaf(b2.y, gv, o2); o3 = fmaf(b3.y, gv, o3);
            gv = gtc[(size_t)(j + 2) * IND];
            o0 = fmaf(b0.z, gv, o0); o1 = fmaf(b1.z, gv, o1);
            o2 = fmaf(b2.z, gv, o2); o3 = fmaf(b3.z, gv, o3);
            gv = gtc[(size_t)(j + 3) * IND];
            o0 = fmaf(b0.w, gv, o0); o1 = fmaf(b1.w, gv, o1);
            o2 = fmaf(b2.w, gv, o2); o3 = fmaf(b3.w, gv, o3);
        }
        s_red[w][0][lane] = o0; s_red[w][1][lane] = o1;
        s_red[w][2][lane] = o2; s_red[w][3][lane] = o3;
    }
    __syncthreads();
    {
        const int ii = tid >> 6, f = tid & 63;
        float s = s_red[0][ii][f] + s_red[1][ii][f] + s_red[2][ii][f] + s_red[3][ii][f];
        out_feat[(size_t)(i0 + ii) * (NH * NF) + h * NF + f] = s;
    }
}

extern "C" void kernel_launch(void* const* d_in, const int* in_sizes, int n_in,
                              void* d_out, int out_size, void* d_ws, size_t ws_size,
                              hipStream_t stream) {
    const float* X   = (const float*)d_in[0];   // h [1,512,512]
    const float* Ws  = (const float*)d_in[1];   // W_source [512,512]
    const float* Wtg = (const float*)d_in[2];   // W_target [512,512]
    const float* aw  = (const float*)d_in[3];   // attn_w [64]
    const int*   adj = (const int*)d_in[4];     // adjacency [512,512,1]

    float* Xt    = (float*)d_ws;                  // [512 k][512 n]
    float* Wtg_t = Xt    + (size_t)NN * IND;      // [512 k][512 o]
    float* Gs_t  = Wtg_t + (size_t)NN * IND;      // [512 o][512 n]
    float* Gt    = Gs_t  + (size_t)NN * IND;      // [512 n][512 o]

    float* out_feat = (float*)d_out;                    // [512,512]
    float* out_att  = out_feat + (size_t)NN * NH * NF;  // [512,512,8]

    hipLaunchKernelGGL(transpose512, dim3(16, 16, 2), dim3(256), 0, stream,
                       X, Xt, Wtg, Wtg_t);
    hipLaunchKernelGGL(gemm_tn, dim3(4, 64, 2), dim3(256), 0, stream,
                       Ws, Xt, Gs_t, X, Wtg_t, Gt);
    hipLaunchKernelGGL(gat_attn, dim3(NN / 4, NH), dim3(256), 0, stream,
                       Gs_t, Gt, aw, adj, out_feat, out_att);
}